// Round 4
// baseline (782.102 us; speedup 1.0000x reference)
//
#include <hip/hip_runtime.h>

#define N_NODES 50000
#define N_EDGES 800000
#define IN_F 96
#define OUT_F 128
#define KCH 4

#define SCAN_B 1024
#define N_SCAN_BLOCKS ((N_NODES + SCAN_B - 1) / SCAN_B)  // 49

// ---------------- CSR build ----------------

__global__ void hist_kernel(const int* __restrict__ rows, int* __restrict__ counts) {
  int e = blockIdx.x * blockDim.x + threadIdx.x;
  if (e < N_EDGES) atomicAdd(&counts[rows[e]], 1);
}

__global__ void scan1_kernel(const int* __restrict__ counts, int* __restrict__ excl,
                             int* __restrict__ bsums) {
  __shared__ int tmp[SCAN_B];
  int tid = threadIdx.x;
  int gid = blockIdx.x * SCAN_B + tid;
  int v = (gid < N_NODES) ? counts[gid] : 0;
  tmp[tid] = v;
  __syncthreads();
  for (int off = 1; off < SCAN_B; off <<= 1) {
    int t = (tid >= off) ? tmp[tid - off] : 0;
    __syncthreads();
    tmp[tid] += t;
    __syncthreads();
  }
  if (gid < N_NODES) excl[gid] = tmp[tid] - v;  // exclusive
  if (tid == SCAN_B - 1) bsums[blockIdx.x] = tmp[tid];
}

__global__ void scan2_kernel(int* __restrict__ bsums) {
  if (threadIdx.x == 0 && blockIdx.x == 0) {
    int acc = 0;
    for (int i = 0; i < N_SCAN_BLOCKS; ++i) {
      int t = bsums[i];
      bsums[i] = acc;
      acc += t;
    }
  }
}

__global__ void scan3_kernel(const int* __restrict__ excl, const int* __restrict__ bsums,
                             int* __restrict__ row_start, int* __restrict__ cursor) {
  int gid = blockIdx.x * blockDim.x + threadIdx.x;
  if (gid < N_NODES) {
    int v = excl[gid] + bsums[gid / SCAN_B];
    row_start[gid] = v;
    cursor[gid] = v;
  }
  if (gid == 0) row_start[N_NODES] = N_EDGES;
}

__global__ void scatter_kernel(const int* __restrict__ rows, const int* __restrict__ cols,
                               const float* __restrict__ vals, int* __restrict__ cursor,
                               int* __restrict__ col_perm, float* __restrict__ val_perm) {
  int e = blockIdx.x * blockDim.x + threadIdx.x;
  if (e < N_EDGES) {
    int r = rows[e];
    int pos = atomicAdd(&cursor[r], 1);
    col_perm[pos] = cols[e];
    val_perm[pos] = vals[e];
  }
}

// ---------------- SpMM with fused recurrence epilogue ----------------
// y[row,:] = alpha * sum_e val[e]*v[col[e],:]  +  beta * prev[row,:]
// one wave per row; lanes 0..63 cover f=lane, lanes 0..31 also cover f=64+lane

__global__ __launch_bounds__(256) void spmm_cheb_kernel(
    const int* __restrict__ row_start, const int* __restrict__ col_perm,
    const float* __restrict__ val_perm, const float* __restrict__ v,
    const float* __restrict__ prev, float alpha, float beta, float* __restrict__ y) {
  int row = blockIdx.x * (blockDim.x >> 6) + (threadIdx.x >> 6);
  if (row >= N_NODES) return;
  int lane = threadIdx.x & 63;
  int s = row_start[row];
  int e = row_start[row + 1];
  float acc0 = 0.f, acc1 = 0.f;
  for (int i = s; i < e; ++i) {
    int c = col_perm[i];
    float val = val_perm[i];
    acc0 += val * v[c * IN_F + lane];
    if (lane < 32) acc1 += val * v[c * IN_F + 64 + lane];
  }
  float p0 = prev[row * IN_F + lane];
  y[row * IN_F + lane] = alpha * acc0 + beta * p0;
  if (lane < 32) {
    float p1 = prev[row * IN_F + 64 + lane];
    y[row * IN_F + 64 + lane] = alpha * acc1 + beta * p1;
  }
}

// ---------------- GEMM: out[n,o] = b[o] + sum_{f,k} T_k[n,f] * W[o, f*4+k] --------
// block: 32 nodes x 128 outs, 256 threads, 4x4 micro-tile per thread

#define BM 32

__global__ __launch_bounds__(256) void gemm_kernel(
    const float* __restrict__ t0, const float* __restrict__ t1,
    const float* __restrict__ t2, const float* __restrict__ t3,
    const float* __restrict__ W, const float* __restrict__ bias,
    float* __restrict__ out) {
  __shared__ float s[BM * 384];  // [ni][k*96+f]
  int tid = threadIdx.x;
  int n0 = blockIdx.x * BM;

  for (int idx = tid; idx < BM * 384; idx += 256) {
    int ni = idx / 384;
    int r = idx - ni * 384;
    int k = r / 96;
    int f = r - k * 96;
    const float* T = (k == 0) ? t0 : (k == 1) ? t1 : (k == 2) ? t2 : t3;
    int n = n0 + ni;
    s[idx] = (n < N_NODES) ? T[n * IN_F + f] : 0.f;
  }
  __syncthreads();

  int og = tid & 31;  // outputs 4*og .. 4*og+3
  int ng = tid >> 5;  // nodes   4*ng .. 4*ng+3
  float acc[4][4];
#pragma unroll
  for (int i = 0; i < 4; ++i)
#pragma unroll
    for (int p = 0; p < 4; ++p) acc[i][p] = 0.f;

  const float* sbase = &s[(4 * ng) * 384];
  const float* wbase = &W[(4 * og) * 384];

#pragma unroll 4
  for (int f = 0; f < 96; ++f) {
    float4 w[4];
#pragma unroll
    for (int p = 0; p < 4; ++p)
      w[p] = *reinterpret_cast<const float4*>(&wbase[p * 384 + f * 4]);
#pragma unroll
    for (int i = 0; i < 4; ++i) {
      float a0 = sbase[i * 384 + 0 * 96 + f];
      float a1 = sbase[i * 384 + 1 * 96 + f];
      float a2 = sbase[i * 384 + 2 * 96 + f];
      float a3 = sbase[i * 384 + 3 * 96 + f];
#pragma unroll
      for (int p = 0; p < 4; ++p)
        acc[i][p] += a0 * w[p].x + a1 * w[p].y + a2 * w[p].z + a3 * w[p].w;
    }
  }

  float4 bv = *reinterpret_cast<const float4*>(&bias[4 * og]);
#pragma unroll
  for (int i = 0; i < 4; ++i) {
    int n = n0 + 4 * ng + i;
    if (n < N_NODES) {
      float4 o;
      o.x = acc[i][0] + bv.x;
      o.y = acc[i][1] + bv.y;
      o.z = acc[i][2] + bv.z;
      o.w = acc[i][3] + bv.w;
      *reinterpret_cast<float4*>(&out[n * OUT_F + 4 * og]) = o;
    }
  }
}

// ---------------- launch ----------------

extern "C" void kernel_launch(void* const* d_in, const int* in_sizes, int n_in,
                              void* d_out, int out_size, void* d_ws, size_t ws_size,
                              hipStream_t stream) {
  const float* x = (const float*)d_in[0];
  const int* lap_rows = (const int*)d_in[1];
  const int* lap_cols = (const int*)d_in[2];
  const float* lap_vals = (const float*)d_in[3];
  const float* W = (const float*)d_in[4];
  const float* b = (const float*)d_in[5];
  float* out = (float*)d_out;

  char* ws = (char*)d_ws;
  float* T1 = (float*)ws;            ws += (size_t)N_NODES * IN_F * 4;
  float* T2 = (float*)ws;            ws += (size_t)N_NODES * IN_F * 4;
  float* T3 = (float*)ws;            ws += (size_t)N_NODES * IN_F * 4;
  int* counts = (int*)ws;            ws += (size_t)N_NODES * 4;
  int* excl = (int*)ws;              ws += (size_t)N_NODES * 4;
  int* row_start = (int*)ws;         ws += (size_t)(N_NODES + 8) * 4;
  int* cursor = (int*)ws;            ws += (size_t)N_NODES * 4;
  int* bsums = (int*)ws;             ws += 64 * 4;
  int* col_perm = (int*)ws;          ws += (size_t)N_EDGES * 4;
  float* val_perm = (float*)ws;      ws += (size_t)N_EDGES * 4;

  hipMemsetAsync(counts, 0, (size_t)N_NODES * 4, stream);

  int eb = (N_EDGES + 255) / 256;
  hist_kernel<<<eb, 256, 0, stream>>>(lap_rows, counts);
  scan1_kernel<<<N_SCAN_BLOCKS, SCAN_B, 0, stream>>>(counts, excl, bsums);
  scan2_kernel<<<1, 64, 0, stream>>>(bsums);
  scan3_kernel<<<(N_NODES + 256) / 256, 256, 0, stream>>>(excl, bsums, row_start, cursor);
  scatter_kernel<<<eb, 256, 0, stream>>>(lap_rows, lap_cols, lap_vals, cursor, col_perm,
                                         val_perm);

  int sb = (N_NODES + 3) / 4;  // 4 rows (waves) per 256-thread block
  spmm_cheb_kernel<<<sb, 256, 0, stream>>>(row_start, col_perm, val_perm, x, x, 1.f, 0.f, T1);
  spmm_cheb_kernel<<<sb, 256, 0, stream>>>(row_start, col_perm, val_perm, T1, x, 2.f, -1.f, T2);
  spmm_cheb_kernel<<<sb, 256, 0, stream>>>(row_start, col_perm, val_perm, T2, T1, 2.f, -1.f, T3);

  int gb = (N_NODES + BM - 1) / BM;
  gemm_kernel<<<gb, 256, 0, stream>>>(x, T1, T2, T3, W, b, out);
}

// Round 5
// 509.098 us; speedup vs baseline: 1.5363x; 1.5363x over previous
//
#include <hip/hip_runtime.h>

#define N_NODES 50000
#define N_PAD 50048          // 782 * 64
#define N_EDGES 800000
#define IN_F 96
#define OUT_F 128
#define KTOT 384             // IN_F * 4, GEMM K dim (f*4+k interleaved)

#define SCAN_B 1024
#define N_SCAN_BLOCKS ((N_NODES + SCAN_B - 1) / SCAN_B)  // 49

typedef __attribute__((ext_vector_type(8))) short bf16x8;
typedef __attribute__((ext_vector_type(4))) float f32x4;

__device__ __forceinline__ short f2bf(float x) {
  union { float f; unsigned u; } c;
  c.f = x;
  unsigned u = c.u;
  u = (u + 0x7FFFu + ((u >> 16) & 1u)) >> 16;  // round-to-nearest-even
  return (short)u;
}

// ---------------- CSR build ----------------

__global__ void hist_kernel(const int* __restrict__ rows, int* __restrict__ counts) {
  int e = blockIdx.x * blockDim.x + threadIdx.x;
  if (e < N_EDGES) atomicAdd(&counts[rows[e]], 1);
}

__global__ void scan1_kernel(const int* __restrict__ counts, int* __restrict__ excl,
                             int* __restrict__ bsums) {
  __shared__ int tmp[SCAN_B];
  int tid = threadIdx.x;
  int gid = blockIdx.x * SCAN_B + tid;
  int v = (gid < N_NODES) ? counts[gid] : 0;
  tmp[tid] = v;
  __syncthreads();
  for (int off = 1; off < SCAN_B; off <<= 1) {
    int t = (tid >= off) ? tmp[tid - off] : 0;
    __syncthreads();
    tmp[tid] += t;
    __syncthreads();
  }
  if (gid < N_NODES) excl[gid] = tmp[tid] - v;  // exclusive
  if (tid == SCAN_B - 1) bsums[blockIdx.x] = tmp[tid];
}

__global__ void scan2_kernel(int* __restrict__ bsums) {
  if (threadIdx.x == 0 && blockIdx.x == 0) {
    int acc = 0;
    for (int i = 0; i < N_SCAN_BLOCKS; ++i) {
      int t = bsums[i];
      bsums[i] = acc;
      acc += t;
    }
  }
}

__global__ void scan3_kernel(const int* __restrict__ excl, const int* __restrict__ bsums,
                             int* __restrict__ row_start, int* __restrict__ cursor) {
  int gid = blockIdx.x * blockDim.x + threadIdx.x;
  if (gid < N_NODES) {
    int v = excl[gid] + bsums[gid / SCAN_B];
    row_start[gid] = v;
    cursor[gid] = v;
  }
  if (gid == 0) row_start[N_NODES] = N_EDGES;
}

__global__ void scatter_kernel(const int* __restrict__ rows, const int* __restrict__ cols,
                               const float* __restrict__ vals, int* __restrict__ cursor,
                               int* __restrict__ col_perm, float* __restrict__ val_perm) {
  int e = blockIdx.x * blockDim.x + threadIdx.x;
  if (e < N_EDGES) {
    int r = rows[e];
    int pos = atomicAdd(&cursor[r], 1);
    col_perm[pos] = cols[e];
    val_perm[pos] = vals[e];
  }
}

// ---------------- dtype prep ----------------

// cheb[n][f*4+0] = bf16(x[n][f])
__global__ void convert_x_kernel(const float* __restrict__ x, short* __restrict__ cheb) {
  int i = blockIdx.x * blockDim.x + threadIdx.x;
  if (i < N_NODES * IN_F) {
    int n = i / IN_F;
    int f = i - n * IN_F;
    cheb[(size_t)n * KTOT + f * 4] = f2bf(x[i]);
  }
}

__global__ void convert_w_kernel(const float* __restrict__ W, short* __restrict__ Wb) {
  int i = blockIdx.x * blockDim.x + threadIdx.x;
  if (i < OUT_F * KTOT) Wb[i] = f2bf(W[i]);
}

// ---------------- SpMM with fused recurrence epilogue ----------------
// r = alpha * (L @ v)[row,:] + beta * prev[row,:]
// write fp32 to y (if y != nullptr) and bf16 to cheb[row][f*4+slot]

__global__ __launch_bounds__(256) void spmm_cheb_kernel(
    const int* __restrict__ row_start, const int* __restrict__ col_perm,
    const float* __restrict__ val_perm, const float* __restrict__ v,
    const float* __restrict__ prev, float alpha, float beta,
    float* __restrict__ y, short* __restrict__ cheb, int slot) {
  int row = blockIdx.x * (blockDim.x >> 6) + (threadIdx.x >> 6);
  if (row >= N_NODES) return;
  int lane = threadIdx.x & 63;
  int s = row_start[row];
  int e = row_start[row + 1];
  float acc0 = 0.f, acc1 = 0.f;
  for (int i = s; i < e; ++i) {
    int c = col_perm[i];
    float val = val_perm[i];
    acc0 += val * v[c * IN_F + lane];
    if (lane < 32) acc1 += val * v[c * IN_F + 64 + lane];
  }
  float p0 = prev[row * IN_F + lane];
  float r0 = alpha * acc0 + beta * p0;
  if (y) y[row * IN_F + lane] = r0;
  cheb[(size_t)row * KTOT + lane * 4 + slot] = f2bf(r0);
  if (lane < 32) {
    float p1 = prev[row * IN_F + 64 + lane];
    float r1 = alpha * acc1 + beta * p1;
    if (y) y[row * IN_F + 64 + lane] = r1;
    cheb[(size_t)row * KTOT + (64 + lane) * 4 + slot] = f2bf(r1);
  }
}

// ---------------- MFMA GEMM: out[n][o] = bias[o] + sum_K cheb[n][K] * W[o][K] ----
// block: 4 waves, 64 nodes x 128 outs. wave w: 64 nodes x outs [32w, 32w+32).
// No LDS: A-frags and B-frags are 16B contiguous global loads (L2-resident W,
// A re-read 4x across waves from L2/L3).

__global__ __launch_bounds__(256) void gemm_mfma_kernel(
    const short* __restrict__ A,   // [N_PAD][384] bf16 (pad rows garbage, masked)
    const short* __restrict__ Bm,  // [128][384] bf16
    const float* __restrict__ bias,
    float* __restrict__ out) {
  int tid = threadIdx.x;
  int wave = tid >> 6;
  int lane = tid & 63;
  int n0 = blockIdx.x * 64;
  int o0 = wave * 32;
  int lr = lane & 15;        // row-in-A-frag / col-in-B-frag
  int lk = (lane >> 4) * 8;  // k offset within frag

  f32x4 acc[4][2];
#pragma unroll
  for (int m = 0; m < 4; ++m)
#pragma unroll
    for (int nn = 0; nn < 2; ++nn) acc[m][nn] = (f32x4){0.f, 0.f, 0.f, 0.f};

  const short* aptr = A + (size_t)(n0 + lr) * KTOT + lk;
  const short* bptr = Bm + (size_t)(o0 + lr) * KTOT + lk;

#pragma unroll 2
  for (int kt = 0; kt < KTOT / 32; ++kt) {
    bf16x8 a[4], b[2];
#pragma unroll
    for (int m = 0; m < 4; ++m)
      a[m] = *reinterpret_cast<const bf16x8*>(aptr + (size_t)m * 16 * KTOT + kt * 32);
#pragma unroll
    for (int nn = 0; nn < 2; ++nn)
      b[nn] = *reinterpret_cast<const bf16x8*>(bptr + (size_t)nn * 16 * KTOT + kt * 32);
#pragma unroll
    for (int m = 0; m < 4; ++m)
#pragma unroll
      for (int nn = 0; nn < 2; ++nn)
        acc[m][nn] = __builtin_amdgcn_mfma_f32_16x16x32_bf16(a[m], b[nn], acc[m][nn], 0, 0, 0);
  }

  int orow = (lane >> 4) * 4;  // C/D: col = lane&15, row = (lane>>4)*4 + reg
#pragma unroll
  for (int m = 0; m < 4; ++m) {
#pragma unroll
    for (int nn = 0; nn < 2; ++nn) {
      int oc = o0 + nn * 16 + lr;
      float bv = bias[oc];
#pragma unroll
      for (int j = 0; j < 4; ++j) {
        int n = n0 + m * 16 + orow + j;
        if (n < N_NODES) out[(size_t)n * OUT_F + oc] = acc[m][nn][j] + bv;
      }
    }
  }
}

// ---------------- launch ----------------

extern "C" void kernel_launch(void* const* d_in, const int* in_sizes, int n_in,
                              void* d_out, int out_size, void* d_ws, size_t ws_size,
                              hipStream_t stream) {
  const float* x = (const float*)d_in[0];
  const int* lap_rows = (const int*)d_in[1];
  const int* lap_cols = (const int*)d_in[2];
  const float* lap_vals = (const float*)d_in[3];
  const float* W = (const float*)d_in[4];
  const float* b = (const float*)d_in[5];
  float* out = (float*)d_out;

  char* ws = (char*)d_ws;
  short* cheb = (short*)ws;          ws += (size_t)N_PAD * KTOT * 2;   // 38.4 MB
  float* T1 = (float*)ws;            ws += (size_t)N_NODES * IN_F * 4; // 19.2 MB
  float* T2 = (float*)ws;            ws += (size_t)N_NODES * IN_F * 4; // 19.2 MB
  short* Wb = (short*)ws;            ws += (size_t)OUT_F * KTOT * 2;   // 96 KB
  int* counts = (int*)ws;            ws += (size_t)N_NODES * 4;
  int* excl = (int*)ws;              ws += (size_t)N_NODES * 4;
  int* row_start = (int*)ws;         ws += (size_t)(N_NODES + 8) * 4;
  int* cursor = (int*)ws;            ws += (size_t)N_NODES * 4;
  int* bsums = (int*)ws;             ws += 64 * 4;
  int* col_perm = (int*)ws;          ws += (size_t)N_EDGES * 4;
  float* val_perm = (float*)ws;      ws += (size_t)N_EDGES * 4;

  hipMemsetAsync(counts, 0, (size_t)N_NODES * 4, stream);

  int eb = (N_EDGES + 255) / 256;
  hist_kernel<<<eb, 256, 0, stream>>>(lap_rows, counts);
  scan1_kernel<<<N_SCAN_BLOCKS, SCAN_B, 0, stream>>>(counts, excl, bsums);
  scan2_kernel<<<1, 64, 0, stream>>>(bsums);
  scan3_kernel<<<(N_NODES + 256) / 256, 256, 0, stream>>>(excl, bsums, row_start, cursor);
  scatter_kernel<<<eb, 256, 0, stream>>>(lap_rows, lap_cols, lap_vals, cursor, col_perm,
                                         val_perm);

  convert_x_kernel<<<(N_NODES * IN_F + 255) / 256, 256, 0, stream>>>(x, cheb);
  convert_w_kernel<<<(OUT_F * KTOT + 255) / 256, 256, 0, stream>>>(W, Wb);

  int sb = (N_NODES + 3) / 4;  // 4 rows (waves) per 256-thread block
  spmm_cheb_kernel<<<sb, 256, 0, stream>>>(row_start, col_perm, val_perm, x, x, 1.f, 0.f,
                                           T1, cheb, 1);
  spmm_cheb_kernel<<<sb, 256, 0, stream>>>(row_start, col_perm, val_perm, T1, x, 2.f, -1.f,
                                           T2, cheb, 2);
  spmm_cheb_kernel<<<sb, 256, 0, stream>>>(row_start, col_perm, val_perm, T2, T1, 2.f, -1.f,
                                           nullptr, cheb, 3);

  gemm_mfma_kernel<<<N_PAD / 64, 256, 0, stream>>>(cheb, Wb, b, out);
}

// Round 6
// 314.830 us; speedup vs baseline: 2.4842x; 1.6171x over previous
//
#include <hip/hip_runtime.h>

#define N_NODES 50000
#define N_PAD 50048          // 782 * 64
#define N_EDGES 800000
#define IN_F 96
#define OUT_F 128
#define KTOT 384             // GEMM K dim, k-major: K = k*96 + f

#define SCAN_B 1024
#define N_SCAN_BLOCKS ((N_NODES + SCAN_B - 1) / SCAN_B)  // 49

typedef __attribute__((ext_vector_type(8))) short bf16x8;
typedef __attribute__((ext_vector_type(4))) float f32x4;

__device__ __forceinline__ short f2bf(float x) {
  union { float f; unsigned u; } c;
  c.f = x;
  unsigned u = c.u;
  u = (u + 0x7FFFu + ((u >> 16) & 1u)) >> 16;  // round-to-nearest-even
  return (short)u;
}

// ---------------- CSR build ----------------

__global__ void hist_kernel(const int* __restrict__ rows, int* __restrict__ counts) {
  int e = blockIdx.x * blockDim.x + threadIdx.x;
  if (e < N_EDGES) atomicAdd(&counts[rows[e]], 1);
}

__global__ void scan1_kernel(const int* __restrict__ counts, int* __restrict__ excl,
                             int* __restrict__ bsums) {
  __shared__ int tmp[SCAN_B];
  int tid = threadIdx.x;
  int gid = blockIdx.x * SCAN_B + tid;
  int v = (gid < N_NODES) ? counts[gid] : 0;
  tmp[tid] = v;
  __syncthreads();
  for (int off = 1; off < SCAN_B; off <<= 1) {
    int t = (tid >= off) ? tmp[tid - off] : 0;
    __syncthreads();
    tmp[tid] += t;
    __syncthreads();
  }
  if (gid < N_NODES) excl[gid] = tmp[tid] - v;  // exclusive
  if (tid == SCAN_B - 1) bsums[blockIdx.x] = tmp[tid];
}

__global__ void scan2_kernel(int* __restrict__ bsums) {
  if (threadIdx.x == 0 && blockIdx.x == 0) {
    int acc = 0;
    for (int i = 0; i < N_SCAN_BLOCKS; ++i) {
      int t = bsums[i];
      bsums[i] = acc;
      acc += t;
    }
  }
}

__global__ void scan3_kernel(const int* __restrict__ excl, const int* __restrict__ bsums,
                             int* __restrict__ row_start, int* __restrict__ cursor) {
  int gid = blockIdx.x * blockDim.x + threadIdx.x;
  if (gid < N_NODES) {
    int v = excl[gid] + bsums[gid / SCAN_B];
    row_start[gid] = v;
    cursor[gid] = v;
  }
  if (gid == 0) row_start[N_NODES] = N_EDGES;
}

__global__ void scatter_kernel(const int* __restrict__ rows, const int* __restrict__ cols,
                               const float* __restrict__ vals, int* __restrict__ cursor,
                               int* __restrict__ col_perm, float* __restrict__ val_perm) {
  int e = blockIdx.x * blockDim.x + threadIdx.x;
  if (e < N_EDGES) {
    int r = rows[e];
    int pos = atomicAdd(&cursor[r], 1);
    col_perm[pos] = cols[e];
    val_perm[pos] = vals[e];
  }
}

// ---------------- dtype prep ----------------

// xb[n][f] = bf16(x[n][f]), contiguous [N][96]; processed as packed dwords
__global__ void convert_x_kernel(const float* __restrict__ x, unsigned* __restrict__ xb) {
  int i = blockIdx.x * blockDim.x + threadIdx.x;  // dword index, 2 feats each
  if (i < N_NODES * 48) {
    float2 v = reinterpret_cast<const float2*>(x)[i];
    xb[i] = (unsigned)(unsigned short)f2bf(v.x) | ((unsigned)(unsigned short)f2bf(v.y) << 16);
  }
}

// Wb[o][k*96+f] = bf16(W[o][f*4+k])  (k-major K axis to match A = [xb|T1b|T2b|T3b])
__global__ void convert_w_kernel(const float* __restrict__ W, short* __restrict__ Wb) {
  int i = blockIdx.x * blockDim.x + threadIdx.x;
  if (i < OUT_F * KTOT) {
    int o = i / KTOT;
    int r = i - o * KTOT;
    int k = r / IN_F;
    int f = r - k * IN_F;
    Wb[i] = f2bf(W[o * KTOT + f * 4 + k]);
  }
}

// ---------------- SpMM, 4-edge-parallel wave, bf16 gather ----------------
// r[row,:] = alpha * sum_e val[e]*vb[col[e],:] + beta * prev[row,:]
// wave = 1 row; 64 lanes = 4 edge-slots x 16 lanes; lane loads 3 dwords/edge
// (dword d = it*16+lid holds feats 2d,2d+1); shfl_xor butterfly over slots.

__global__ __launch_bounds__(256) void spmm_cheb_kernel(
    const int* __restrict__ row_start, const int* __restrict__ col_perm,
    const float* __restrict__ val_perm,
    const short* __restrict__ vb,    // bf16 [N][96] gather source
    const float* __restrict__ prev,  // fp32 [N][96]
    float alpha, float beta,
    float* __restrict__ y,           // fp32 [N][96] out (or null)
    unsigned* __restrict__ yb) {     // bf16 [N][96] out as dwords
  int row = blockIdx.x * 4 + (threadIdx.x >> 6);
  if (row >= N_NODES) return;
  int lane = threadIdx.x & 63;
  int eslot = lane >> 4;  // 0..3
  int lid = lane & 15;    // 0..15
  int s = row_start[row];
  int e = row_start[row + 1];

  float acc[6];
#pragma unroll
  for (int i = 0; i < 6; ++i) acc[i] = 0.f;

#pragma unroll 2
  for (int base = s; base < e; base += 4) {
    int idx = base + eslot;
    int c = 0;
    float val = 0.f;
    if (idx < e) {
      c = col_perm[idx];
      val = val_perm[idx];
    }
    const unsigned* srcd = reinterpret_cast<const unsigned*>(vb + (size_t)c * IN_F);
#pragma unroll
    for (int it = 0; it < 3; ++it) {
      unsigned dv = srcd[it * 16 + lid];
      union { unsigned u; float f; } a0, a1;
      a0.u = dv << 16;
      a1.u = dv & 0xffff0000u;
      acc[2 * it] += val * a0.f;
      acc[2 * it + 1] += val * a1.f;
    }
  }

#pragma unroll
  for (int i = 0; i < 6; ++i) {
    acc[i] += __shfl_xor(acc[i], 16);
    acc[i] += __shfl_xor(acc[i], 32);
  }

  if (eslot < 3) {
    int f0 = eslot * 32 + lid * 2;  // this lane writes feats f0, f0+1
    float2 p = *reinterpret_cast<const float2*>(prev + (size_t)row * IN_F + f0);
    float r0 = alpha * acc[2 * eslot] + beta * p.x;
    float r1 = alpha * acc[2 * eslot + 1] + beta * p.y;
    if (y) *reinterpret_cast<float2*>(y + (size_t)row * IN_F + f0) = make_float2(r0, r1);
    yb[(size_t)row * 48 + (f0 >> 1)] =
        (unsigned)(unsigned short)f2bf(r0) | ((unsigned)(unsigned short)f2bf(r1) << 16);
  }
}

// ---------------- MFMA GEMM: out[n][o] = bias[o] + sum_K A[n][K] * Wb[o][K] ----
// A = concat_K of 4 bf16 [N][96] segments. Block: 4 waves, 64 nodes x 128 outs.

__global__ __launch_bounds__(256) void gemm_mfma_kernel(
    const short* __restrict__ s0, const short* __restrict__ s1,
    const short* __restrict__ s2, const short* __restrict__ s3,
    const short* __restrict__ Bm,  // [128][384] bf16, k-major K
    const float* __restrict__ bias,
    float* __restrict__ out) {
  int tid = threadIdx.x;
  int wave = tid >> 6;
  int lane = tid & 63;
  int n0 = blockIdx.x * 64;
  int o0 = wave * 32;
  int lr = lane & 15;        // row-in-A-frag / col-in-B-frag
  int lk = (lane >> 4) * 8;  // k offset within frag

  f32x4 acc[4][2];
#pragma unroll
  for (int m = 0; m < 4; ++m)
#pragma unroll
    for (int nn = 0; nn < 2; ++nn) acc[m][nn] = (f32x4){0.f, 0.f, 0.f, 0.f};

  const short* segs[4] = {s0, s1, s2, s3};
  const short* bptr = Bm + (size_t)(o0 + lr) * KTOT + lk;

#pragma unroll
  for (int seg = 0; seg < 4; ++seg) {
    const short* aseg = segs[seg] + (size_t)(n0 + lr) * IN_F + lk;
#pragma unroll
    for (int t = 0; t < 3; ++t) {
      int kt = seg * 3 + t;
      bf16x8 a[4], b[2];
#pragma unroll
      for (int m = 0; m < 4; ++m)
        a[m] = *reinterpret_cast<const bf16x8*>(aseg + (size_t)m * 16 * IN_F + t * 32);
#pragma unroll
      for (int nn = 0; nn < 2; ++nn)
        b[nn] = *reinterpret_cast<const bf16x8*>(bptr + (size_t)nn * 16 * KTOT + kt * 32);
#pragma unroll
      for (int m = 0; m < 4; ++m)
#pragma unroll
        for (int nn = 0; nn < 2; ++nn)
          acc[m][nn] = __builtin_amdgcn_mfma_f32_16x16x32_bf16(a[m], b[nn], acc[m][nn], 0, 0, 0);
    }
  }

  int orow = (lane >> 4) * 4;  // C/D: col = lane&15, row = (lane>>4)*4 + reg
#pragma unroll
  for (int m = 0; m < 4; ++m) {
#pragma unroll
    for (int nn = 0; nn < 2; ++nn) {
      int oc = o0 + nn * 16 + lr;
      float bv = bias[oc];
#pragma unroll
      for (int j = 0; j < 4; ++j) {
        int n = n0 + m * 16 + orow + j;
        if (n < N_NODES) out[(size_t)n * OUT_F + oc] = acc[m][nn][j] + bv;
      }
    }
  }
}

// ---------------- launch ----------------

extern "C" void kernel_launch(void* const* d_in, const int* in_sizes, int n_in,
                              void* d_out, int out_size, void* d_ws, size_t ws_size,
                              hipStream_t stream) {
  const float* x = (const float*)d_in[0];
  const int* lap_rows = (const int*)d_in[1];
  const int* lap_cols = (const int*)d_in[2];
  const float* lap_vals = (const float*)d_in[3];
  const float* W = (const float*)d_in[4];
  const float* b = (const float*)d_in[5];
  float* out = (float*)d_out;

  char* ws = (char*)d_ws;
  short* xb = (short*)ws;            ws += (size_t)N_NODES * IN_F * 2;  // 9.6 MB
  short* T1b = (short*)ws;           ws += (size_t)N_NODES * IN_F * 2;
  short* T2b = (short*)ws;           ws += (size_t)N_NODES * IN_F * 2;
  short* T3b = (short*)ws;           ws += (size_t)N_NODES * IN_F * 2;
  float* T1 = (float*)ws;            ws += (size_t)N_NODES * IN_F * 4;  // 19.2 MB
  float* T2 = (float*)ws;            ws += (size_t)N_NODES * IN_F * 4;
  short* Wb = (short*)ws;            ws += (size_t)OUT_F * KTOT * 2;    // 96 KB
  int* counts = (int*)ws;            ws += 200192;
  int* excl = (int*)ws;              ws += 200192;
  int* row_start = (int*)ws;         ws += 200192;
  int* cursor = (int*)ws;            ws += 200192;
  int* bsums = (int*)ws;             ws += 256;
  int* col_perm = (int*)ws;          ws += (size_t)N_EDGES * 4;
  float* val_perm = (float*)ws;      ws += (size_t)N_EDGES * 4;

  hipMemsetAsync(counts, 0, (size_t)N_NODES * 4, stream);

  int eb = (N_EDGES + 255) / 256;
  hist_kernel<<<eb, 256, 0, stream>>>(lap_rows, counts);
  scan1_kernel<<<N_SCAN_BLOCKS, SCAN_B, 0, stream>>>(counts, excl, bsums);
  scan2_kernel<<<1, 64, 0, stream>>>(bsums);
  scan3_kernel<<<(N_NODES + 256) / 256, 256, 0, stream>>>(excl, bsums, row_start, cursor);
  scatter_kernel<<<eb, 256, 0, stream>>>(lap_rows, lap_cols, lap_vals, cursor, col_perm,
                                         val_perm);

  convert_x_kernel<<<(N_NODES * 48 + 255) / 256, 256, 0, stream>>>(x, (unsigned*)xb);
  convert_w_kernel<<<(OUT_F * KTOT + 255) / 256, 256, 0, stream>>>(W, Wb);

  int sb = (N_NODES + 3) / 4;  // 1 row per wave, 4 waves per block
  spmm_cheb_kernel<<<sb, 256, 0, stream>>>(row_start, col_perm, val_perm, xb, x, 1.f, 0.f,
                                           T1, (unsigned*)T1b);
  spmm_cheb_kernel<<<sb, 256, 0, stream>>>(row_start, col_perm, val_perm, T1b, x, 2.f, -1.f,
                                           T2, (unsigned*)T2b);
  spmm_cheb_kernel<<<sb, 256, 0, stream>>>(row_start, col_perm, val_perm, T2b, T1, 2.f, -1.f,
                                           nullptr, (unsigned*)T3b);

  gemm_mfma_kernel<<<N_PAD / 64, 256, 0, stream>>>(xb, T1b, T2b, T3b, Wb, b, out);
}

// Round 7
// 301.141 us; speedup vs baseline: 2.5971x; 1.0455x over previous
//
#include <hip/hip_runtime.h>

#define N_NODES 50000
#define N_PAD 50048          // 782 * 64
#define N_EDGES 800000
#define IN_F 96
#define OUT_F 128
#define KTOT 384             // GEMM K dim, k-major: K = k*96 + f

#define SCAN_B 1024
#define N_SCAN_BLOCKS ((N_NODES + SCAN_B - 1) / SCAN_B)  // 49

typedef __attribute__((ext_vector_type(8))) short bf16x8;
typedef __attribute__((ext_vector_type(4))) float f32x4;

__device__ __forceinline__ short f2bf(float x) {
  union { float f; unsigned u; } c;
  c.f = x;
  unsigned u = c.u;
  u = (u + 0x7FFFu + ((u >> 16) & 1u)) >> 16;  // round-to-nearest-even
  return (short)u;
}

__device__ __forceinline__ float bflo(unsigned u) {
  union { unsigned u; float f; } c;
  c.u = u << 16;
  return c.f;
}
__device__ __forceinline__ float bfhi(unsigned u) {
  union { unsigned u; float f; } c;
  c.u = u & 0xffff0000u;
  return c.f;
}

// ---------------- CSR build ----------------

__global__ void hist_kernel(const int* __restrict__ rows, int* __restrict__ counts) {
  int e = blockIdx.x * blockDim.x + threadIdx.x;
  if (e < N_EDGES) atomicAdd(&counts[rows[e]], 1);
}

__global__ void scan1_kernel(const int* __restrict__ counts, int* __restrict__ excl,
                             int* __restrict__ bsums) {
  __shared__ int tmp[SCAN_B];
  int tid = threadIdx.x;
  int gid = blockIdx.x * SCAN_B + tid;
  int v = (gid < N_NODES) ? counts[gid] : 0;
  tmp[tid] = v;
  __syncthreads();
  for (int off = 1; off < SCAN_B; off <<= 1) {
    int t = (tid >= off) ? tmp[tid - off] : 0;
    __syncthreads();
    tmp[tid] += t;
    __syncthreads();
  }
  if (gid < N_NODES) excl[gid] = tmp[tid] - v;  // exclusive
  if (tid == SCAN_B - 1) bsums[blockIdx.x] = tmp[tid];
}

__global__ void scan2_kernel(int* __restrict__ bsums) {
  if (threadIdx.x == 0 && blockIdx.x == 0) {
    int acc = 0;
    for (int i = 0; i < N_SCAN_BLOCKS; ++i) {
      int t = bsums[i];
      bsums[i] = acc;
      acc += t;
    }
  }
}

__global__ void scan3_kernel(const int* __restrict__ excl, const int* __restrict__ bsums,
                             int* __restrict__ row_start, int* __restrict__ cursor) {
  int gid = blockIdx.x * blockDim.x + threadIdx.x;
  if (gid < N_NODES) {
    int v = excl[gid] + bsums[gid / SCAN_B];
    row_start[gid] = v;
    cursor[gid] = v;
  }
  if (gid == 0) row_start[N_NODES] = N_EDGES;
}

// one 8B record per edge: {col, val-bits} — halves scattered stores vs 2x4B
__global__ void scatter_kernel(const int* __restrict__ rows, const int* __restrict__ cols,
                               const float* __restrict__ vals, int* __restrict__ cursor,
                               int2* __restrict__ recs) {
  int e = blockIdx.x * blockDim.x + threadIdx.x;
  if (e < N_EDGES) {
    int r = rows[e];
    int pos = atomicAdd(&cursor[r], 1);
    int2 rec;
    rec.x = cols[e];
    rec.y = __float_as_int(vals[e]);
    recs[pos] = rec;
  }
}

// ---------------- dtype prep ----------------

// xb[n][f] = bf16(x[n][f]), contiguous [N][96]; processed as packed dwords
__global__ void convert_x_kernel(const float* __restrict__ x, unsigned* __restrict__ xb) {
  int i = blockIdx.x * blockDim.x + threadIdx.x;  // dword index, 2 feats each
  if (i < N_NODES * 48) {
    float2 v = reinterpret_cast<const float2*>(x)[i];
    xb[i] = (unsigned)(unsigned short)f2bf(v.x) | ((unsigned)(unsigned short)f2bf(v.y) << 16);
  }
}

// Wb[o][k*96+f] = bf16(W[o][f*4+k])  (k-major K axis to match A = [xb|T1b|T2b|T3b])
__global__ void convert_w_kernel(const float* __restrict__ W, short* __restrict__ Wb) {
  int i = blockIdx.x * blockDim.x + threadIdx.x;
  if (i < OUT_F * KTOT) {
    int o = i / KTOT;
    int r = i - o * KTOT;
    int k = r / IN_F;
    int f = r - k * IN_F;
    Wb[i] = f2bf(W[o * KTOT + f * 4 + k]);
  }
}

// ---------------- SpMM, 4-edge-parallel wave, all-bf16 ----------------
// r[row,:] = alpha * sum_e val[e]*vb[col[e],:] + beta * prevb[row,:]
// wave = 1 row; 64 lanes = 4 edge-slots x 16 lanes; lane loads 3 dwords/edge
// (dword d = it*16+lid holds feats 2d,2d+1); shfl_xor butterfly over slots.

__global__ __launch_bounds__(256) void spmm_cheb_kernel(
    const int* __restrict__ row_start, const int2* __restrict__ recs,
    const short* __restrict__ vb,     // bf16 [N][96] gather source
    const short* __restrict__ prevb,  // bf16 [N][96]
    float alpha, float beta,
    unsigned* __restrict__ yb) {      // bf16 [N][96] out as dwords
  int row = blockIdx.x * 4 + (threadIdx.x >> 6);
  if (row >= N_NODES) return;
  int lane = threadIdx.x & 63;
  int eslot = lane >> 4;  // 0..3
  int lid = lane & 15;    // 0..15
  int s = row_start[row];
  int e = row_start[row + 1];

  float acc[6];
#pragma unroll
  for (int i = 0; i < 6; ++i) acc[i] = 0.f;

#pragma unroll 2
  for (int base = s; base < e; base += 4) {
    int idx = base + eslot;
    int c = 0;
    float val = 0.f;
    if (idx < e) {
      int2 rec = recs[idx];
      c = rec.x;
      val = __int_as_float(rec.y);
    }
    const unsigned* srcd = reinterpret_cast<const unsigned*>(vb + (size_t)c * IN_F);
#pragma unroll
    for (int it = 0; it < 3; ++it) {
      unsigned dv = srcd[it * 16 + lid];
      acc[2 * it] += val * bflo(dv);
      acc[2 * it + 1] += val * bfhi(dv);
    }
  }

#pragma unroll
  for (int i = 0; i < 6; ++i) {
    acc[i] += __shfl_xor(acc[i], 16);
    acc[i] += __shfl_xor(acc[i], 32);
  }

  if (eslot < 3) {
    int d = eslot * 16 + lid;  // dword index 0..47, feats 2d, 2d+1
    unsigned pv = reinterpret_cast<const unsigned*>(prevb + (size_t)row * IN_F)[d];
    float r0 = alpha * acc[2 * eslot] + beta * bflo(pv);
    float r1 = alpha * acc[2 * eslot + 1] + beta * bfhi(pv);
    yb[(size_t)row * 48 + d] =
        (unsigned)(unsigned short)f2bf(r0) | ((unsigned)(unsigned short)f2bf(r1) << 16);
  }
}

// ---------------- MFMA GEMM: out[n][o] = bias[o] + sum_K A[n][K] * Wb[o][K] ----
// A = concat_K of 4 bf16 [N][96] segments. Block: 4 waves, 64 nodes x 128 outs.

__global__ __launch_bounds__(256) void gemm_mfma_kernel(
    const short* __restrict__ s0, const short* __restrict__ s1,
    const short* __restrict__ s2, const short* __restrict__ s3,
    const short* __restrict__ Bm,  // [128][384] bf16, k-major K
    const float* __restrict__ bias,
    float* __restrict__ out) {
  int tid = threadIdx.x;
  int wave = tid >> 6;
  int lane = tid & 63;
  int n0 = blockIdx.x * 64;
  int o0 = wave * 32;
  int lr = lane & 15;        // row-in-A-frag / col-in-B-frag
  int lk = (lane >> 4) * 8;  // k offset within frag

  f32x4 acc[4][2];
#pragma unroll
  for (int m = 0; m < 4; ++m)
#pragma unroll
    for (int nn = 0; nn < 2; ++nn) acc[m][nn] = (f32x4){0.f, 0.f, 0.f, 0.f};

  const short* segs[4] = {s0, s1, s2, s3};
  const short* bptr = Bm + (size_t)(o0 + lr) * KTOT + lk;

#pragma unroll
  for (int seg = 0; seg < 4; ++seg) {
    const short* aseg = segs[seg] + (size_t)(n0 + lr) * IN_F + lk;
#pragma unroll
    for (int t = 0; t < 3; ++t) {
      int kt = seg * 3 + t;
      bf16x8 a[4], b[2];
#pragma unroll
      for (int m = 0; m < 4; ++m)
        a[m] = *reinterpret_cast<const bf16x8*>(aseg + (size_t)m * 16 * IN_F + t * 32);
#pragma unroll
      for (int nn = 0; nn < 2; ++nn)
        b[nn] = *reinterpret_cast<const bf16x8*>(bptr + (size_t)nn * 16 * KTOT + kt * 32);
#pragma unroll
      for (int m = 0; m < 4; ++m)
#pragma unroll
        for (int nn = 0; nn < 2; ++nn)
          acc[m][nn] = __builtin_amdgcn_mfma_f32_16x16x32_bf16(a[m], b[nn], acc[m][nn], 0, 0, 0);
    }
  }

  int orow = (lane >> 4) * 4;  // C/D: col = lane&15, row = (lane>>4)*4 + reg
#pragma unroll
  for (int m = 0; m < 4; ++m) {
#pragma unroll
    for (int nn = 0; nn < 2; ++nn) {
      int oc = o0 + nn * 16 + lr;
      float bv = bias[oc];
#pragma unroll
      for (int j = 0; j < 4; ++j) {
        int n = n0 + m * 16 + orow + j;
        if (n < N_NODES) out[(size_t)n * OUT_F + oc] = acc[m][nn][j] + bv;
      }
    }
  }
}

// ---------------- launch ----------------

extern "C" void kernel_launch(void* const* d_in, const int* in_sizes, int n_in,
                              void* d_out, int out_size, void* d_ws, size_t ws_size,
                              hipStream_t stream) {
  const float* x = (const float*)d_in[0];
  const int* lap_rows = (const int*)d_in[1];
  const int* lap_cols = (const int*)d_in[2];
  const float* lap_vals = (const float*)d_in[3];
  const float* W = (const float*)d_in[4];
  const float* b = (const float*)d_in[5];
  float* out = (float*)d_out;

  char* ws = (char*)d_ws;
  short* xb = (short*)ws;            ws += (size_t)N_NODES * IN_F * 2;  // 9.6 MB
  short* T1b = (short*)ws;           ws += (size_t)N_NODES * IN_F * 2;
  short* T2b = (short*)ws;           ws += (size_t)N_NODES * IN_F * 2;
  short* T3b = (short*)ws;           ws += (size_t)N_NODES * IN_F * 2;
  short* Wb = (short*)ws;            ws += (size_t)OUT_F * KTOT * 2;    // 96 KB
  int* counts = (int*)ws;            ws += 200192;
  int* excl = (int*)ws;              ws += 200192;
  int* row_start = (int*)ws;         ws += 200192;
  int* cursor = (int*)ws;            ws += 200192;
  int* bsums = (int*)ws;             ws += 256;
  int2* recs = (int2*)ws;            ws += (size_t)N_EDGES * 8;         // 6.4 MB

  hipMemsetAsync(counts, 0, (size_t)N_NODES * 4, stream);

  int eb = (N_EDGES + 255) / 256;
  hist_kernel<<<eb, 256, 0, stream>>>(lap_rows, counts);
  scan1_kernel<<<N_SCAN_BLOCKS, SCAN_B, 0, stream>>>(counts, excl, bsums);
  scan2_kernel<<<1, 64, 0, stream>>>(bsums);
  scan3_kernel<<<(N_NODES + 256) / 256, 256, 0, stream>>>(excl, bsums, row_start, cursor);
  scatter_kernel<<<eb, 256, 0, stream>>>(lap_rows, lap_cols, lap_vals, cursor, recs);

  convert_x_kernel<<<(N_NODES * 48 + 255) / 256, 256, 0, stream>>>(x, (unsigned*)xb);
  convert_w_kernel<<<(OUT_F * KTOT + 255) / 256, 256, 0, stream>>>(W, Wb);

  int sb = (N_NODES + 3) / 4;  // 1 row per wave, 4 waves per block
  spmm_cheb_kernel<<<sb, 256, 0, stream>>>(row_start, recs, xb, xb, 1.f, 0.f,
                                           (unsigned*)T1b);
  spmm_cheb_kernel<<<sb, 256, 0, stream>>>(row_start, recs, T1b, xb, 2.f, -1.f,
                                           (unsigned*)T2b);
  spmm_cheb_kernel<<<sb, 256, 0, stream>>>(row_start, recs, T2b, T1b, 2.f, -1.f,
                                           (unsigned*)T3b);

  gemm_mfma_kernel<<<N_PAD / 64, 256, 0, stream>>>(xb, T1b, T2b, T3b, Wb, b, out);
}